// Round 4
// baseline (1100.186 us; speedup 1.0000x reference)
//
#include <hip/hip_runtime.h>

#define NN 25000
#define EE 400000
#define FIN 128
#define FE 16
#define CH 32
#define SLOPE 0.01f
#define PROJ_BLOCKS 391   // ceil(25000/64)
#define AUX_BLOCKS 32
#define WROW 24                      // WtL row stride in shorts (48B = 16B-multiple)
#define WTP_SHORTS (1024 * WROW)     // 48KB image, plain layout (rotation reverted: it HURT)
#define EPB 256                      // edges per k_edge tile
#define NTILES ((EE + EPB - 1) / EPB)  // 1563 (last tile ragged: 128 valid edges)
#define PBLK 512                     // persistent blocks = 2 per CU exactly

typedef __attribute__((ext_vector_type(8))) short bf16x8;
typedef __attribute__((ext_vector_type(4))) float f32x4;

__device__ __forceinline__ float lrelu(float v) { return fmaxf(v, SLOPE * v); }

__device__ __forceinline__ f32x4 lrelu4(f32x4 v) {
    f32x4 s = v * SLOPE;
#if __has_builtin(__builtin_elementwise_max)
    return __builtin_elementwise_max(v, s);   // v_pk_max_f32
#else
    f32x4 r;
    r[0] = fmaxf(v[0], s[0]); r[1] = fmaxf(v[1], s[1]);
    r[2] = fmaxf(v[2], s[2]); r[3] = fmaxf(v[3], s[3]);
    return r;
#endif
}

// float -> bf16 bits, round-to-nearest-even
__device__ __forceinline__ short f2bf(float f) {
    union { float f; unsigned u; } v; v.f = f;
    unsigned r = (v.u + 0x7fffu + ((v.u >> 16) & 1u)) >> 16;
    return (short)r;
}

__device__ __forceinline__ int eclamp(int i) { return i < EE ? i : EE - 1; }

// ---------------- Kernel 1: fused prep
// blocks [0, PROJ_BLOCKS): h = leaky(x @ W_in + b_in) via MFMA (64 nodes/block)
// blocks [PROJ, +4): WtP[co][24] = {bf16 W_edge^T row, bias@16, zeros} (plain layout)
// blocks [+4, +32): zero aggr
__global__ void __launch_bounds__(256)
k_pre(const float* __restrict__ x, const float* __restrict__ W_in,
      const float* __restrict__ b_in, const float* __restrict__ W_edge,
      const float* __restrict__ b_edge,
      float* __restrict__ h, float* __restrict__ aggr, short* __restrict__ WtP) {
    __shared__ short Wt1[CH * 136];
    int tid = threadIdx.x;

    if (blockIdx.x >= PROJ_BLOCKS) {
        int ab = blockIdx.x - PROJ_BLOCKS;
        if (ab < 4) {
            int co = ab * 256 + tid;                       // 0..1023
            short row[WROW] __attribute__((aligned(16)));
#pragma unroll
            for (int k = 0; k < 16; k++) row[k] = f2bf(W_edge[k * 1024 + co]);
            row[16] = f2bf(b_edge[co]);
#pragma unroll
            for (int k = 17; k < WROW; k++) row[k] = 0;
            uint4* dstp = (uint4*)(WtP + co * WROW);       // co*48B, 16B-aligned
            dstp[0] = ((uint4*)row)[0]; dstp[1] = ((uint4*)row)[1]; dstp[2] = ((uint4*)row)[2];
        } else {
            int t = (ab - 4) * 256 + tid;
            float4 z = make_float4(0.f, 0.f, 0.f, 0.f);
            for (int i = t; i < NN * CH / 4; i += (AUX_BLOCKS - 4) * 256)
                ((float4*)aggr)[i] = z;
        }
        return;
    }

    // ---- input projection ----
#pragma unroll
    for (int i = 0; i < 16; i++) {
        int id = tid + 256 * i;           // id = k*32 + c
        int k = id >> 5, c = id & 31;
        Wt1[c * 136 + k] = f2bf(W_in[id]);
    }
    __syncthreads();

    int wave = tid >> 6, lane = tid & 63;
    int n16 = lane & 15, quad = lane >> 4;
    int node0 = blockIdx.x * 64 + wave * 16;

    f32x4 D[2];
#pragma unroll
    for (int ch = 0; ch < 2; ch++) {
        float bb = b_in[ch * 16 + n16];
        D[ch] = (f32x4){bb, bb, bb, bb};
    }
    int arow = node0 + n16; if (arow >= NN) arow = NN - 1;
#pragma unroll
    for (int kb = 0; kb < 4; kb++) {
        const float4* xp = (const float4*)(x + (size_t)arow * FIN + kb * 32 + quad * 8);
        float4 xa = xp[0], xb = xp[1];
        bf16x8 A = (bf16x8){f2bf(xa.x), f2bf(xa.y), f2bf(xa.z), f2bf(xa.w),
                            f2bf(xb.x), f2bf(xb.y), f2bf(xb.z), f2bf(xb.w)};
#pragma unroll
        for (int ch = 0; ch < 2; ch++) {
            bf16x8 B = *(const bf16x8*)&Wt1[(ch * 16 + n16) * 136 + kb * 32 + quad * 8];
            D[ch] = __builtin_amdgcn_mfma_f32_16x16x32_bf16(A, B, D[ch], 0, 0, 0);
        }
    }
#pragma unroll
    for (int ch = 0; ch < 2; ch++)
#pragma unroll
        for (int r = 0; r < 4; r++) {
            int nn = node0 + quad * 4 + r;
            if (nn < NN) h[(size_t)nn * CH + ch * 16 + n16] = lrelu(D[ch][r]);
        }
}

// ---------------- Kernel 2: persistent, TRANSPOSED-MFMA edge kernel
// D[co][edge] = mfma(A = WtL-frag (We^T rows), B = ea-frag (registers, no LDS)).
// col = edge = n16  =>  h multiplier is ONE scalar per lane per c.
// Wave owns 64 edges (4 B-frags) => one WtL A-read feeds 4 MFMAs (was 2 MFMAs per read).
// hsT stored e-transposed: phys(e) = (e&15)*16 + (e>>4), so a lane's 4 group-scalars
// h[g0..g3][c] are ONE contiguous f32x4 read (2-way banks = free).
// LDS per 64-edge wave-tile: 64 WtL b128 + 32 h b128 (was 512 b128 per 128-edge tile).
// LDS = 49152 (WtL) + 32768 (hsT[32][256]) = 81920 B exactly -> 2 blocks/CU.
// quad3's A-read aliases qoff=0 (its B-frag is zeros we build in regs -> A bits don't-care),
// so no tail pad needed. Bias folded at K=16 (A reads {bias,0..} row; B quad2 = {1.0,0..}).
__global__ void __launch_bounds__(256, 2)
k_edge(const short* __restrict__ WtP,    // [1024][24] bf16 image (plain)
       const float* __restrict__ ea,     // [EE][16] f32
       const int* __restrict__ src,
       const int* __restrict__ dst,
       const float* __restrict__ h,
       float* __restrict__ aggr) {
    __shared__ short WtL[WTP_SHORTS];        // 49152 B
    __shared__ float hsT[CH * EPB];          // 32768 B, hsT[c][phys(e)]

    int tid = threadIdx.x;

    // stage WtL once per persistent block: 3072 uint4 (48KB)
#pragma unroll
    for (int j = 0; j < 12; j++) {
        int idx = tid + 256 * j;
        ((uint4*)WtL)[idx] = ((const uint4*)WtP)[idx];
    }

    int wave = tid >> 6, lane = tid & 63;
    int n16 = lane & 15, quad = lane >> 4;
    int wbase = wave * 64;

    // gather role: thread tid handles logical edge eT; its phys slot is then
    // (tid>>4)*16 + (tid&15) -> write banks 2-way (free)
    int eT = ((tid & 15) << 4) | (tid >> 4);
    int physo = (tid >> 4) * 16 + (tid & 15);

    int qoff = (quad == 3) ? 0 : quad * 8;
    const short* Abase = WtL + n16 * WROW + qoff;        // + cb*384 shorts (imm)
    const float* hbase = hsT + n16 * 16 + wave * 4;      // + c*256 (imm)

    struct Pref {
        float4 ear[8];    // quads 0,1: ea rows (g*16+n16), 2 float4 each, g=0..3
        int dstv[4];
    };
    Pref Pa, Pb;

    auto PREF = [&](int tile, Pref& P) {
        int base = tile * EPB;
        if (quad < 2) {
#pragma unroll
            for (int g = 0; g < 4; g++) {
                const float4* p = (const float4*)(ea + (size_t)eclamp(base + wbase + g * 16 + n16) * FE + quad * 8);
                P.ear[2 * g] = p[0]; P.ear[2 * g + 1] = p[1];
            }
        }
#pragma unroll
        for (int g = 0; g < 4; g++)
            P.dstv[g] = dst[eclamp(base + wbase + g * 16 + n16)];
    };

    auto CONVERT = [&](Pref& P, bf16x8* B) {
        if (quad < 2) {
#pragma unroll
            for (int g = 0; g < 4; g++) {
                float4 a = P.ear[2 * g], b = P.ear[2 * g + 1];
                B[g] = (bf16x8){f2bf(a.x), f2bf(a.y), f2bf(a.z), f2bf(a.w),
                                f2bf(b.x), f2bf(b.y), f2bf(b.z), f2bf(b.w)};
            }
        } else if (quad == 2) {
#pragma unroll
            for (int g = 0; g < 4; g++) {
                B[g] = (bf16x8){0,0,0,0,0,0,0,0};
                B[g][0] = (short)0x3F80;                 // bf16 1.0 at k=16 (bias row)
            }
        } else {
#pragma unroll
            for (int g = 0; g < 4; g++) B[g] = (bf16x8){0,0,0,0,0,0,0,0};
        }
    };

    auto COMPUTE = [&](int tile, const bf16x8* B, const int* dstv) {
        const f32x4 Z = (f32x4){0, 0, 0, 0};
        f32x4 m[4][2];
#pragma unroll
        for (int g = 0; g < 4; g++) { m[g][0] = Z; m[g][1] = Z; }

#pragma unroll
        for (int c = 0; c < 32; c++) {
            f32x4 hv = *(const f32x4*)(hbase + c * EPB);   // h[g0..3][c], 2-way banks
#pragma unroll
            for (int oh = 0; oh < 2; oh++) {
                bf16x8 A = *(const bf16x8*)(Abase + (c * 2 + oh) * (16 * WROW));
                f32x4 D0 = __builtin_amdgcn_mfma_f32_16x16x32_bf16(A, B[0], Z, 0, 0, 0);
                f32x4 D1 = __builtin_amdgcn_mfma_f32_16x16x32_bf16(A, B[1], Z, 0, 0, 0);
                f32x4 D2 = __builtin_amdgcn_mfma_f32_16x16x32_bf16(A, B[2], Z, 0, 0, 0);
                f32x4 D3 = __builtin_amdgcn_mfma_f32_16x16x32_bf16(A, B[3], Z, 0, 0, 0);
                m[0][oh] += lrelu4(D0) * hv[0];
                m[1][oh] += lrelu4(D1) * hv[1];
                m[2][oh] += lrelu4(D2) * hv[2];
                m[3][oh] += lrelu4(D3) * hv[3];
            }
        }

        // scatter: lane's edge e_g = tile*256 + wbase + g*16 + n16 (col), o = oh*16+quad*4+r (row)
        int base = tile * EPB;
#pragma unroll
        for (int g = 0; g < 4; g++) {
            int e = base + wbase + g * 16 + n16;
            if (e < EE) {
                float* ap = aggr + (size_t)dstv[g] * CH;
#pragma unroll
                for (int oh = 0; oh < 2; oh++)
#pragma unroll
                    for (int r = 0; r < 4; r++)
                        unsafeAtomicAdd(ap + oh * 16 + quad * 4 + r, m[g][oh][r]);
            }
        }
    };

    // ---- persistent loop, phase-unrolled x2 (static Pa/Pb, rule: no dynamic indexing)
    int tile = blockIdx.x;
    int sc = src[eclamp(tile * EPB + eT)];
    PREF(tile, Pa);
    bf16x8 B[4];
    while (true) {
        {   // phase A: consume (sc, Pa), prefetch Pb
            const float4* hp = (const float4*)(h + (size_t)sc * CH);
            float4 h0 = hp[0], h1 = hp[1], h2 = hp[2], h3 = hp[3];
            float4 h4 = hp[4], h5 = hp[5], h6 = hp[6], h7 = hp[7];
            int nt = tile + PBLK; bool more = (nt < NTILES);
            int sn; if (more) sn = src[eclamp(nt * EPB + eT)];
            __syncthreads();                      // prev COMPUTE done reading hsT
            float hv[32] __attribute__((aligned(16)));
            *(float4*)&hv[0] = h0;  *(float4*)&hv[4] = h1;
            *(float4*)&hv[8] = h2;  *(float4*)&hv[12] = h3;
            *(float4*)&hv[16] = h4; *(float4*)&hv[20] = h5;
            *(float4*)&hv[24] = h6; *(float4*)&hv[28] = h7;
#pragma unroll
            for (int c = 0; c < 32; c++) hsT[c * EPB + physo] = hv[c];
            __syncthreads();                      // hsT ready
            CONVERT(Pa, B);
            if (more) PREF(nt, Pb);               // flies during COMPUTE
            COMPUTE(tile, B, Pa.dstv);
            if (!more) break;
            tile = nt; sc = sn;
        }
        {   // phase B: consume (sc, Pb), prefetch Pa
            const float4* hp = (const float4*)(h + (size_t)sc * CH);
            float4 h0 = hp[0], h1 = hp[1], h2 = hp[2], h3 = hp[3];
            float4 h4 = hp[4], h5 = hp[5], h6 = hp[6], h7 = hp[7];
            int nt = tile + PBLK; bool more = (nt < NTILES);
            int sn; if (more) sn = src[eclamp(nt * EPB + eT)];
            __syncthreads();
            float hv[32] __attribute__((aligned(16)));
            *(float4*)&hv[0] = h0;  *(float4*)&hv[4] = h1;
            *(float4*)&hv[8] = h2;  *(float4*)&hv[12] = h3;
            *(float4*)&hv[16] = h4; *(float4*)&hv[20] = h5;
            *(float4*)&hv[24] = h6; *(float4*)&hv[28] = h7;
#pragma unroll
            for (int c = 0; c < 32; c++) hsT[c * EPB + physo] = hv[c];
            __syncthreads();
            CONVERT(Pb, B);
            if (more) PREF(nt, Pa);
            COMPUTE(tile, B, Pb.dstv);
            if (!more) break;
            tile = nt; sc = sn;
        }
    }
}

// ---------------- Kernel 3 (MFMA): out = leaky(aggr + h@W_root + b_conv) @ W_out + b_out
__global__ void __launch_bounds__(256)
k_node(const float* __restrict__ aggr,
       const float* __restrict__ h,
       const float* __restrict__ W_root,
       const float* __restrict__ b_conv,
       const float* __restrict__ W_out,
       const float* __restrict__ b_out,
       float* __restrict__ out) {
    __shared__ short WrB[CH * 40];   // W_root^T bf16: [o][c], stride 40 shorts (80B)
    __shared__ float WoS[CH];
    int tid = threadIdx.x;
    if (tid < 128) {
        int o = tid >> 2, c0 = (tid & 3) * 8;
        short tmp[8] __attribute__((aligned(16)));
#pragma unroll
        for (int j = 0; j < 8; j++) tmp[j] = f2bf(W_root[(c0 + j) * CH + o]);
        *(bf16x8*)&WrB[o * 40 + c0] = *(bf16x8*)tmp;
    } else if (tid < 160) {
        WoS[tid - 128] = W_out[tid - 128];
    }
    __syncthreads();

    int wave = tid >> 6, lane = tid & 63;
    int n16 = lane & 15, quad = lane >> 4;
    int node0 = blockIdx.x * 64 + wave * 16;

    int arow = node0 + n16; if (arow >= NN) arow = NN - 1;
    const float4* hp = (const float4*)(h + (size_t)arow * CH + quad * 8);
    float4 ha = hp[0], hb = hp[1];
    bf16x8 A = (bf16x8){f2bf(ha.x), f2bf(ha.y), f2bf(ha.z), f2bf(ha.w),
                        f2bf(hb.x), f2bf(hb.y), f2bf(hb.z), f2bf(hb.w)};
    float bc0 = b_conv[n16], bc1 = b_conv[16 + n16];
    f32x4 C0, C1;
#pragma unroll
    for (int r = 0; r < 4; r++) {
        int nr = node0 + quad * 4 + r; int cr = (nr < NN) ? nr : NN - 1;
        C0[r] = aggr[(size_t)cr * CH + n16] + bc0;
        C1[r] = aggr[(size_t)cr * CH + 16 + n16] + bc1;
    }
    bf16x8 B0 = *(const bf16x8*)&WrB[n16 * 40 + quad * 8];
    bf16x8 B1 = *(const bf16x8*)&WrB[(16 + n16) * 40 + quad * 8];
    f32x4 D0 = __builtin_amdgcn_mfma_f32_16x16x32_bf16(A, B0, C0, 0, 0, 0);
    f32x4 D1 = __builtin_amdgcn_mfma_f32_16x16x32_bf16(A, B1, C1, 0, 0, 0);

    float w0 = WoS[n16], w1 = WoS[16 + n16];
    f32x4 p;
#pragma unroll
    for (int r = 0; r < 4; r++)
        p[r] = lrelu(D0[r]) * w0 + lrelu(D1[r]) * w1;
#pragma unroll
    for (int mk = 1; mk < 16; mk <<= 1) {
#pragma unroll
        for (int r = 0; r < 4; r++) p[r] += __shfl_xor(p[r], mk, 64);
    }
    if (n16 == 0) {
        float bo = b_out[0];
#pragma unroll
        for (int r = 0; r < 4; r++) {
            int nr = node0 + quad * 4 + r;
            if (nr < NN) out[nr] = p[r] + bo;
        }
    }
}

extern "C" void kernel_launch(void* const* d_in, const int* in_sizes, int n_in,
                              void* d_out, int out_size, void* d_ws, size_t ws_size,
                              hipStream_t stream) {
    const float* x      = (const float*)d_in[0];
    const int*   ei     = (const int*)d_in[1];
    const float* ea     = (const float*)d_in[2];
    const float* W_in   = (const float*)d_in[3];
    const float* b_in   = (const float*)d_in[4];
    const float* W_edge = (const float*)d_in[5];
    const float* b_edge = (const float*)d_in[6];
    const float* W_root = (const float*)d_in[7];
    const float* b_conv = (const float*)d_in[8];
    const float* W_out  = (const float*)d_in[9];
    const float* b_out  = (const float*)d_in[10];
    float* out  = (float*)d_out;
    float* h    = (float*)d_ws;                  // [NN*CH] f32
    float* aggr = h + (size_t)NN * CH;           // [NN*CH] f32
    short* WtP  = (short*)(aggr + (size_t)NN * CH);  // [WTP_SHORTS] bf16 image

    k_pre<<<PROJ_BLOCKS + AUX_BLOCKS, 256, 0, stream>>>(x, W_in, b_in, W_edge, b_edge,
                                                        h, aggr, WtP);
    k_edge<<<PBLK, 256, 0, stream>>>(WtP, ea, ei, ei + EE, h, aggr);
    k_node<<<PROJ_BLOCKS, 256, 0, stream>>>(aggr, h, W_root, b_conv, W_out, b_out, out);
}

// Round 5
// 684.766 us; speedup vs baseline: 1.6067x; 1.6067x over previous
//
#include <hip/hip_runtime.h>

#define NN 25000
#define EE 400000
#define FIN 128
#define FE 16
#define CH 32
#define SLOPE 0.01f
#define PROJ_BLOCKS 391   // ceil(25000/64)
#define AUX_BLOCKS 32
#define WROW 24                      // WtL row stride in shorts (48B = 16B-multiple)
#define WTP_SHORTS (1024 * WROW)     // 48KB image
#define EPB 256                      // edges per k_edge tile
#define NTILES ((EE + EPB - 1) / EPB)  // 1563 (last tile ragged: 128 valid edges)
#define PBLK 1024                    // persistent blocks: 1-2 tiles each (balance)

typedef __attribute__((ext_vector_type(8))) short bf16x8;
typedef __attribute__((ext_vector_type(4))) float f32x4;

__device__ __forceinline__ float lrelu(float v) { return fmaxf(v, SLOPE * v); }

__device__ __forceinline__ f32x4 lrelu4(f32x4 v) {
    f32x4 s = v * SLOPE;
#if __has_builtin(__builtin_elementwise_max)
    return __builtin_elementwise_max(v, s);   // v_pk_max_f32
#else
    f32x4 r;
    r[0] = fmaxf(v[0], s[0]); r[1] = fmaxf(v[1], s[1]);
    r[2] = fmaxf(v[2], s[2]); r[3] = fmaxf(v[3], s[3]);
    return r;
#endif
}

// float -> bf16 bits, round-to-nearest-even
__device__ __forceinline__ short f2bf(float f) {
    union { float f; unsigned u; } v; v.f = f;
    unsigned r = (v.u + 0x7fffu + ((v.u >> 16) & 1u)) >> 16;
    return (short)r;
}

__device__ __forceinline__ bf16x8 cvt8(const float4& a, const float4& b) {
    return (bf16x8){f2bf(a.x), f2bf(a.y), f2bf(a.z), f2bf(a.w),
                    f2bf(b.x), f2bf(b.y), f2bf(b.z), f2bf(b.w)};
}

__device__ __forceinline__ int eclamp(int i) { return i < EE ? i : EE - 1; }

// ---------------- Kernel 1: fused prep (unchanged from R4 - verified)
__global__ void __launch_bounds__(256)
k_pre(const float* __restrict__ x, const float* __restrict__ W_in,
      const float* __restrict__ b_in, const float* __restrict__ W_edge,
      const float* __restrict__ b_edge,
      float* __restrict__ h, float* __restrict__ aggr, short* __restrict__ WtP) {
    __shared__ short Wt1[CH * 136];
    int tid = threadIdx.x;

    if (blockIdx.x >= PROJ_BLOCKS) {
        int ab = blockIdx.x - PROJ_BLOCKS;
        if (ab < 4) {
            int co = ab * 256 + tid;                       // 0..1023
            short row[WROW] __attribute__((aligned(16)));
#pragma unroll
            for (int k = 0; k < 16; k++) row[k] = f2bf(W_edge[k * 1024 + co]);
            row[16] = f2bf(b_edge[co]);
#pragma unroll
            for (int k = 17; k < WROW; k++) row[k] = 0;
            uint4* dstp = (uint4*)(WtP + co * WROW);       // co*48B, 16B-aligned
            dstp[0] = ((uint4*)row)[0]; dstp[1] = ((uint4*)row)[1]; dstp[2] = ((uint4*)row)[2];
        } else {
            int t = (ab - 4) * 256 + tid;
            float4 z = make_float4(0.f, 0.f, 0.f, 0.f);
            for (int i = t; i < NN * CH / 4; i += (AUX_BLOCKS - 4) * 256)
                ((float4*)aggr)[i] = z;
        }
        return;
    }

#pragma unroll
    for (int i = 0; i < 16; i++) {
        int id = tid + 256 * i;           // id = k*32 + c
        int k = id >> 5, c = id & 31;
        Wt1[c * 136 + k] = f2bf(W_in[id]);
    }
    __syncthreads();

    int wave = tid >> 6, lane = tid & 63;
    int n16 = lane & 15, quad = lane >> 4;
    int node0 = blockIdx.x * 64 + wave * 16;

    f32x4 D[2];
#pragma unroll
    for (int ch = 0; ch < 2; ch++) {
        float bb = b_in[ch * 16 + n16];
        D[ch] = (f32x4){bb, bb, bb, bb};
    }
    int arow = node0 + n16; if (arow >= NN) arow = NN - 1;
#pragma unroll
    for (int kb = 0; kb < 4; kb++) {
        const float4* xp = (const float4*)(x + (size_t)arow * FIN + kb * 32 + quad * 8);
        float4 xa = xp[0], xb = xp[1];
        bf16x8 A = cvt8(xa, xb);
#pragma unroll
        for (int ch = 0; ch < 2; ch++) {
            bf16x8 B = *(const bf16x8*)&Wt1[(ch * 16 + n16) * 136 + kb * 32 + quad * 8];
            D[ch] = __builtin_amdgcn_mfma_f32_16x16x32_bf16(A, B, D[ch], 0, 0, 0);
        }
    }
#pragma unroll
    for (int ch = 0; ch < 2; ch++)
#pragma unroll
        for (int r = 0; r < 4; r++) {
            int nn = node0 + quad * 4 + r;
            if (nn < NN) h[(size_t)nn * CH + ch * 16 + n16] = lrelu(D[ch][r]);
        }
}

// ---------------- Kernel 2: persistent TRANSPOSED-MFMA edge kernel (R4 math, de-spilled)
// D[co][edge] = mfma(A = WtL row-frags, B = ea in registers). Wave owns 64 edges:
// 1 A-read (b128) feeds 4 MFMAs; h multiplier is 1 f32x4 per c covering all 4 groups.
// LDS instrs: ~1.5 b128/edge (was 4/edge in the R0/R3 orientation).
// __launch_bounds__(256, 1): empirical hipcc rule cap = 256/arg2 (R1:(512,4)->64,
// R2:(512,2)->128, R4:(256,2)->128 SPILLED). Cap 256 removes the spill; LDS (80KiB)
// still limits residency to 2 blocks/CU = 2 waves/SIMD, which 256 VGPRs permits.
__global__ void __launch_bounds__(256, 1)
k_edge(const short* __restrict__ WtP,    // [1024][24] bf16 image
       const float* __restrict__ ea,     // [EE][16] f32
       const int* __restrict__ src,
       const int* __restrict__ dst,
       const float* __restrict__ h,
       float* __restrict__ aggr) {
    __shared__ short WtL[WTP_SHORTS];        // 49152 B
    __shared__ float hsT[CH * EPB];          // 32768 B, hsT[c][phys(e)]

    int tid = threadIdx.x;

    // stage WtL once per persistent block: 3072 uint4 (48KB)
#pragma unroll
    for (int j = 0; j < 12; j++) {
        int idx = tid + 256 * j;
        ((uint4*)WtL)[idx] = ((const uint4*)WtP)[idx];
    }

    const int lane = tid & 63;
    const int wave = tid >> 6;
    const int n16 = lane & 15, quad = lane >> 4;
    const int wbase = wave * 64;
    // gather role: thread handles logical edge eT; phys slot = linear tid-order
    const int eT = ((tid & 15) << 4) | (tid >> 4);
    const int physo = (tid >> 4) * 16 + (tid & 15);

    const int qoff = (quad == 3) ? 0 : quad * 8;   // quad3: A bits don't-care (B3=0)
    const short* Abase = WtL + n16 * WROW + qoff;  // + cb*16*WROW (imm)
    const float* hbase = hsT + n16 * 16 + wave * 4;  // + c*EPB (imm)

    // B frags: quads 2 (bias row: bf16 1.0 at k=16) and 3 (zero) are TILE-INVARIANT.
    bf16x8 B0 = (bf16x8){0,0,0,0,0,0,0,0}, B1 = B0, B2 = B0, B3 = B0;
    if (quad == 2) {
        B0[0] = (short)0x3F80; B1[0] = (short)0x3F80;
        B2[0] = (short)0x3F80; B3[0] = (short)0x3F80;
    }

    const f32x4 Z = (f32x4){0, 0, 0, 0};

    int T = blockIdx.x;

    // ---- prologue: tile T state in registers
    int srow = src[eclamp(T * EPB + eT)];
    float4 h0, h1, h2, h3, h4, h5, h6, h7;
    {
        const float4* hp = (const float4*)(h + (size_t)srow * CH);
        h0 = hp[0]; h1 = hp[1]; h2 = hp[2]; h3 = hp[3];
        h4 = hp[4]; h5 = hp[5]; h6 = hp[6]; h7 = hp[7];
    }
    float4 e0, e1, e2, e3, e4, e5, e6, e7;
    if (quad < 2) {
        int b = T * EPB + wbase + n16;
        const float4* p;
        p = (const float4*)(ea + (size_t)eclamp(b)      * FE + quad * 8); e0 = p[0]; e1 = p[1];
        p = (const float4*)(ea + (size_t)eclamp(b + 16) * FE + quad * 8); e2 = p[0]; e3 = p[1];
        p = (const float4*)(ea + (size_t)eclamp(b + 32) * FE + quad * 8); e4 = p[0]; e5 = p[1];
        p = (const float4*)(ea + (size_t)eclamp(b + 48) * FE + quad * 8); e6 = p[0]; e7 = p[1];
    }
    int dv0, dv1, dv2, dv3;
    {
        int b = T * EPB + wbase + n16;
        dv0 = dst[eclamp(b)];      dv1 = dst[eclamp(b + 16)];
        dv2 = dst[eclamp(b + 32)]; dv3 = dst[eclamp(b + 48)];
    }
    if (quad < 2) { B0 = cvt8(e0, e1); B1 = cvt8(e2, e3); B2 = cvt8(e4, e5); B3 = cvt8(e6, e7); }
    srow = src[eclamp((T + PBLK) * EPB + eT)];   // src-row for NEXT tile

    while (true) {
        __syncthreads();                 // hsT free (prev COMPUTE done; 1st iter: staging fence)
        // stream this tile's h row into hsT (32 ds_write_b32, constant offsets)
#define HST(c, v) hsT[(c) * EPB + physo] = (v)
        HST(0, h0.x);  HST(1, h0.y);  HST(2, h0.z);  HST(3, h0.w);
        HST(4, h1.x);  HST(5, h1.y);  HST(6, h1.z);  HST(7, h1.w);
        HST(8, h2.x);  HST(9, h2.y);  HST(10, h2.z); HST(11, h2.w);
        HST(12, h3.x); HST(13, h3.y); HST(14, h3.z); HST(15, h3.w);
        HST(16, h4.x); HST(17, h4.y); HST(18, h4.z); HST(19, h4.w);
        HST(20, h5.x); HST(21, h5.y); HST(22, h5.z); HST(23, h5.w);
        HST(24, h6.x); HST(25, h6.y); HST(26, h6.z); HST(27, h6.w);
        HST(28, h7.x); HST(29, h7.y); HST(30, h7.z); HST(31, h7.w);
#undef HST
        __syncthreads();                 // hsT ready
        int nt = T + PBLK;
        bool more = (nt < NTILES);
        int dn0 = 0, dn1 = 0, dn2 = 0, dn3 = 0, srn = 0;
        if (more) {
            // prefetch next tile: flies under COMPUTE below
            const float4* hp = (const float4*)(h + (size_t)srow * CH);
            h0 = hp[0]; h1 = hp[1]; h2 = hp[2]; h3 = hp[3];
            h4 = hp[4]; h5 = hp[5]; h6 = hp[6]; h7 = hp[7];
            if (quad < 2) {
                int b = nt * EPB + wbase + n16;
                const float4* p;
                p = (const float4*)(ea + (size_t)eclamp(b)      * FE + quad * 8); e0 = p[0]; e1 = p[1];
                p = (const float4*)(ea + (size_t)eclamp(b + 16) * FE + quad * 8); e2 = p[0]; e3 = p[1];
                p = (const float4*)(ea + (size_t)eclamp(b + 32) * FE + quad * 8); e4 = p[0]; e5 = p[1];
                p = (const float4*)(ea + (size_t)eclamp(b + 48) * FE + quad * 8); e6 = p[0]; e7 = p[1];
            }
            int b = nt * EPB + wbase + n16;
            dn0 = dst[eclamp(b)];      dn1 = dst[eclamp(b + 16)];
            dn2 = dst[eclamp(b + 32)]; dn3 = dst[eclamp(b + 48)];
            srn = src[eclamp((nt + PBLK) * EPB + eT)];
        }

        // ---- COMPUTE tile T
        f32x4 m00 = Z, m01 = Z, m10 = Z, m11 = Z, m20 = Z, m21 = Z, m30 = Z, m31 = Z;
#pragma unroll
        for (int c = 0; c < 32; c++) {
            f32x4 hv = *(const f32x4*)(hbase + c * EPB);   // h[g0..3][c], broadcast-free
            {
                bf16x8 A = *(const bf16x8*)(Abase + (c * 2 + 0) * (16 * WROW));
                f32x4 D0 = __builtin_amdgcn_mfma_f32_16x16x32_bf16(A, B0, Z, 0, 0, 0);
                f32x4 D1 = __builtin_amdgcn_mfma_f32_16x16x32_bf16(A, B1, Z, 0, 0, 0);
                f32x4 D2 = __builtin_amdgcn_mfma_f32_16x16x32_bf16(A, B2, Z, 0, 0, 0);
                f32x4 D3 = __builtin_amdgcn_mfma_f32_16x16x32_bf16(A, B3, Z, 0, 0, 0);
                m00 += lrelu4(D0) * hv[0]; m10 += lrelu4(D1) * hv[1];
                m20 += lrelu4(D2) * hv[2]; m30 += lrelu4(D3) * hv[3];
            }
            {
                bf16x8 A = *(const bf16x8*)(Abase + (c * 2 + 1) * (16 * WROW));
                f32x4 D0 = __builtin_amdgcn_mfma_f32_16x16x32_bf16(A, B0, Z, 0, 0, 0);
                f32x4 D1 = __builtin_amdgcn_mfma_f32_16x16x32_bf16(A, B1, Z, 0, 0, 0);
                f32x4 D2 = __builtin_amdgcn_mfma_f32_16x16x32_bf16(A, B2, Z, 0, 0, 0);
                f32x4 D3 = __builtin_amdgcn_mfma_f32_16x16x32_bf16(A, B3, Z, 0, 0, 0);
                m01 += lrelu4(D0) * hv[0]; m11 += lrelu4(D1) * hv[1];
                m21 += lrelu4(D2) * hv[2]; m31 += lrelu4(D3) * hv[3];
            }
        }

        // ---- scatter tile T: edge = T*EPB + wbase + g*16 + n16, channel = oh*16 + quad*4 + r
        {
            int eb = T * EPB + wbase + n16;
            if (eb < EE) {
                float* ap = aggr + (size_t)dv0 * CH + quad * 4;
#pragma unroll
                for (int r = 0; r < 4; r++) {
                    unsafeAtomicAdd(ap + r, m00[r]);
                    unsafeAtomicAdd(ap + 16 + r, m01[r]);
                }
            }
            if (eb + 16 < EE) {
                float* ap = aggr + (size_t)dv1 * CH + quad * 4;
#pragma unroll
                for (int r = 0; r < 4; r++) {
                    unsafeAtomicAdd(ap + r, m10[r]);
                    unsafeAtomicAdd(ap + 16 + r, m11[r]);
                }
            }
            if (eb + 32 < EE) {
                float* ap = aggr + (size_t)dv2 * CH + quad * 4;
#pragma unroll
                for (int r = 0; r < 4; r++) {
                    unsafeAtomicAdd(ap + r, m20[r]);
                    unsafeAtomicAdd(ap + 16 + r, m21[r]);
                }
            }
            if (eb + 48 < EE) {
                float* ap = aggr + (size_t)dv3 * CH + quad * 4;
#pragma unroll
                for (int r = 0; r < 4; r++) {
                    unsafeAtomicAdd(ap + r, m30[r]);
                    unsafeAtomicAdd(ap + 16 + r, m31[r]);
                }
            }
        }

        if (!more) break;
        // rotate state -> next tile
        if (quad < 2) { B0 = cvt8(e0, e1); B1 = cvt8(e2, e3); B2 = cvt8(e4, e5); B3 = cvt8(e6, e7); }
        dv0 = dn0; dv1 = dn1; dv2 = dn2; dv3 = dn3;
        srow = srn;
        T = nt;
    }
}

// ---------------- Kernel 3 (MFMA): out = leaky(aggr + h@W_root + b_conv) @ W_out + b_out
__global__ void __launch_bounds__(256)
k_node(const float* __restrict__ aggr,
       const float* __restrict__ h,
       const float* __restrict__ W_root,
       const float* __restrict__ b_conv,
       const float* __restrict__ W_out,
       const float* __restrict__ b_out,
       float* __restrict__ out) {
    __shared__ short WrB[CH * 40];   // W_root^T bf16: [o][c], stride 40 shorts (80B)
    __shared__ float WoS[CH];
    int tid = threadIdx.x;
    if (tid < 128) {
        int o = tid >> 2, c0 = (tid & 3) * 8;
        short tmp[8] __attribute__((aligned(16)));
#pragma unroll
        for (int j = 0; j < 8; j++) tmp[j] = f2bf(W_root[(c0 + j) * CH + o]);
        *(bf16x8*)&WrB[o * 40 + c0] = *(bf16x8*)tmp;
    } else if (tid < 160) {
        WoS[tid - 128] = W_out[tid - 128];
    }
    __syncthreads();

    int wave = tid >> 6, lane = tid & 63;
    int n16 = lane & 15, quad = lane >> 4;
    int node0 = blockIdx.x * 64 + wave * 16;

    int arow = node0 + n16; if (arow >= NN) arow = NN - 1;
    const float4* hp = (const float4*)(h + (size_t)arow * CH + quad * 8);
    float4 ha = hp[0], hb = hp[1];
    bf16x8 A = cvt8(ha, hb);
    float bc0 = b_conv[n16], bc1 = b_conv[16 + n16];
    f32x4 C0, C1;
#pragma unroll
    for (int r = 0; r < 4; r++) {
        int nr = node0 + quad * 4 + r; int cr = (nr < NN) ? nr : NN - 1;
        C0[r] = aggr[(size_t)cr * CH + n16] + bc0;
        C1[r] = aggr[(size_t)cr * CH + 16 + n16] + bc1;
    }
    bf16x8 B0 = *(const bf16x8*)&WrB[n16 * 40 + quad * 8];
    bf16x8 B1 = *(const bf16x8*)&WrB[(16 + n16) * 40 + quad * 8];
    f32x4 D0 = __builtin_amdgcn_mfma_f32_16x16x32_bf16(A, B0, C0, 0, 0, 0);
    f32x4 D1 = __builtin_amdgcn_mfma_f32_16x16x32_bf16(A, B1, C1, 0, 0, 0);

    float w0 = WoS[n16], w1 = WoS[16 + n16];
    f32x4 p;
#pragma unroll
    for (int r = 0; r < 4; r++)
        p[r] = lrelu(D0[r]) * w0 + lrelu(D1[r]) * w1;
#pragma unroll
    for (int mk = 1; mk < 16; mk <<= 1) {
#pragma unroll
        for (int r = 0; r < 4; r++) p[r] += __shfl_xor(p[r], mk, 64);
    }
    if (n16 == 0) {
        float bo = b_out[0];
#pragma unroll
        for (int r = 0; r < 4; r++) {
            int nr = node0 + quad * 4 + r;
            if (nr < NN) out[nr] = p[r] + bo;
        }
    }
}

extern "C" void kernel_launch(void* const* d_in, const int* in_sizes, int n_in,
                              void* d_out, int out_size, void* d_ws, size_t ws_size,
                              hipStream_t stream) {
    const float* x      = (const float*)d_in[0];
    const int*   ei     = (const int*)d_in[1];
    const float* ea     = (const float*)d_in[2];
    const float* W_in   = (const float*)d_in[3];
    const float* b_in   = (const float*)d_in[4];
    const float* W_edge = (const float*)d_in[5];
    const float* b_edge = (const float*)d_in[6];
    const float* W_root = (const float*)d_in[7];
    const float* b_conv = (const float*)d_in[8];
    const float* W_out  = (const float*)d_in[9];
    const float* b_out  = (const float*)d_in[10];
    float* out  = (float*)d_out;
    float* h    = (float*)d_ws;                  // [NN*CH] f32
    float* aggr = h + (size_t)NN * CH;           // [NN*CH] f32
    short* WtP  = (short*)(aggr + (size_t)NN * CH);  // [WTP_SHORTS] bf16 image

    k_pre<<<PROJ_BLOCKS + AUX_BLOCKS, 256, 0, stream>>>(x, W_in, b_in, W_edge, b_edge,
                                                        h, aggr, WtP);
    k_edge<<<PBLK, 256, 0, stream>>>(WtP, ea, ei, ei + EE, h, aggr);
    k_node<<<PROJ_BLOCKS, 256, 0, stream>>>(aggr, h, W_root, b_conv, W_out, b_out, out);
}

// Round 6
// 186.756 us; speedup vs baseline: 5.8910x; 3.6666x over previous
//
#include <hip/hip_runtime.h>

#define NN 25000
#define EE 400000
#define FIN 128
#define FE 16
#define CH 32
#define SLOPE 0.01f
#define PROJ_BLOCKS 391   // ceil(25000/64)
#define AUX_BLOCKS 32
#define WROW 24                      // WtL row stride in shorts (48B = 16B-multiple)
#define WTP_SHORTS (1024 * WROW)     // 48KB image
#define EPB 256                      // edges per k_edge tile
#define NTILES ((EE + EPB - 1) / EPB)  // 1563 (last tile ragged: 128 valid edges)
#define PBLK 1024                    // persistent blocks: 1-2 tiles each

typedef __attribute__((ext_vector_type(8))) short bf16x8;
typedef __attribute__((ext_vector_type(4))) float f32x4;

__device__ __forceinline__ float lrelu(float v) { return fmaxf(v, SLOPE * v); }

__device__ __forceinline__ f32x4 lrelu4(f32x4 v) {
    f32x4 s = v * SLOPE;
#if __has_builtin(__builtin_elementwise_max)
    return __builtin_elementwise_max(v, s);   // v_pk_max_f32
#else
    f32x4 r;
    r[0] = fmaxf(v[0], s[0]); r[1] = fmaxf(v[1], s[1]);
    r[2] = fmaxf(v[2], s[2]); r[3] = fmaxf(v[3], s[3]);
    return r;
#endif
}

// float -> bf16 bits, round-to-nearest-even
__device__ __forceinline__ short f2bf(float f) {
    union { float f; unsigned u; } v; v.f = f;
    unsigned r = (v.u + 0x7fffu + ((v.u >> 16) & 1u)) >> 16;
    return (short)r;
}

__device__ __forceinline__ bf16x8 cvt8(const float4& a, const float4& b) {
    return (bf16x8){f2bf(a.x), f2bf(a.y), f2bf(a.z), f2bf(a.w),
                    f2bf(b.x), f2bf(b.y), f2bf(b.z), f2bf(b.w)};
}

__device__ __forceinline__ int eclamp(int i) { return i < EE ? i : EE - 1; }

// ---------------- Kernel 1: fused prep (unchanged - verified)
__global__ void __launch_bounds__(256)
k_pre(const float* __restrict__ x, const float* __restrict__ W_in,
      const float* __restrict__ b_in, const float* __restrict__ W_edge,
      const float* __restrict__ b_edge,
      float* __restrict__ h, float* __restrict__ aggr, short* __restrict__ WtP) {
    __shared__ short Wt1[CH * 136];
    int tid = threadIdx.x;

    if (blockIdx.x >= PROJ_BLOCKS) {
        int ab = blockIdx.x - PROJ_BLOCKS;
        if (ab < 4) {
            int co = ab * 256 + tid;                       // 0..1023
            short row[WROW] __attribute__((aligned(16)));
#pragma unroll
            for (int k = 0; k < 16; k++) row[k] = f2bf(W_edge[k * 1024 + co]);
            row[16] = f2bf(b_edge[co]);
#pragma unroll
            for (int k = 17; k < WROW; k++) row[k] = 0;
            uint4* dstp = (uint4*)(WtP + co * WROW);       // co*48B, 16B-aligned
            dstp[0] = ((uint4*)row)[0]; dstp[1] = ((uint4*)row)[1]; dstp[2] = ((uint4*)row)[2];
        } else {
            int t = (ab - 4) * 256 + tid;
            float4 z = make_float4(0.f, 0.f, 0.f, 0.f);
            for (int i = t; i < NN * CH / 4; i += (AUX_BLOCKS - 4) * 256)
                ((float4*)aggr)[i] = z;
        }
        return;
    }

#pragma unroll
    for (int i = 0; i < 16; i++) {
        int id = tid + 256 * i;           // id = k*32 + c
        int k = id >> 5, c = id & 31;
        Wt1[c * 136 + k] = f2bf(W_in[id]);
    }
    __syncthreads();

    int wave = tid >> 6, lane = tid & 63;
    int n16 = lane & 15, quad = lane >> 4;
    int node0 = blockIdx.x * 64 + wave * 16;

    f32x4 D[2];
#pragma unroll
    for (int ch = 0; ch < 2; ch++) {
        float bb = b_in[ch * 16 + n16];
        D[ch] = (f32x4){bb, bb, bb, bb};
    }
    int arow = node0 + n16; if (arow >= NN) arow = NN - 1;
#pragma unroll
    for (int kb = 0; kb < 4; kb++) {
        const float4* xp = (const float4*)(x + (size_t)arow * FIN + kb * 32 + quad * 8);
        float4 xa = xp[0], xb = xp[1];
        bf16x8 A = cvt8(xa, xb);
#pragma unroll
        for (int ch = 0; ch < 2; ch++) {
            bf16x8 B = *(const bf16x8*)&Wt1[(ch * 16 + n16) * 136 + kb * 32 + quad * 8];
            D[ch] = __builtin_amdgcn_mfma_f32_16x16x32_bf16(A, B, D[ch], 0, 0, 0);
        }
    }
#pragma unroll
    for (int ch = 0; ch < 2; ch++)
#pragma unroll
        for (int r = 0; r < 4; r++) {
            int nn = node0 + quad * 4 + r;
            if (nn < NN) h[(size_t)nn * CH + ch * 16 + n16] = lrelu(D[ch][r]);
        }
}

// ---------------- Kernel 2: persistent TRANSPOSED-MFMA edge kernel, coalesced scatter
// Compute: D[co][edge] = mfma(A = WtL row-frags, B = ea in regs). 1 A-read feeds 4 MFMAs.
// R5 post-mortem fixes:
//  (1) hsT physical col P(e) = 64*(e>>6) + 4*(e&15) + ((e>>4)&3)  (writer col = tid):
//      hv f32x4 reads go from 8-way bank conflict (n16*16 stride) to 2-way (free).
//  (2) scatter: m is transposed through hsT (reused as 256x32 msg buffer, wave-private
//      64-col segments, rotation (eloc+ch)&63) so each atomic instruction covers
//      lanes = 32 consecutive channels of ONE dst row (2 rows/instr, 128B contiguous).
//      R5's per-lane-row atomics caused ~2.3GB of uncoalesced RMW HBM traffic = 770us.
// Barriers: 2 per tile (after h-stage; after COMPUTE before msg reuse). msg write->read
// is same-wave ordered via lgkmcnt(0).
// __launch_bounds__(256,1): empirical hipcc VGPR cap = 256/arg2 (R1/R2/R4/R5 evidence).
__global__ void __launch_bounds__(256, 1)
k_edge(const short* __restrict__ WtP,    // [1024][24] bf16 image
       const float* __restrict__ ea,     // [EE][16] f32
       const int* __restrict__ src,
       const int* __restrict__ dst,
       const float* __restrict__ h,
       float* __restrict__ aggr) {
    __shared__ short WtL[WTP_SHORTS];        // 49152 B
    __shared__ float hsT[CH * EPB];          // 32768 B: h-stage [c][P(e)] / msg [ch][col]

    int tid = threadIdx.x;

    // stage WtL once per persistent block: 3072 uint4 (48KB)
#pragma unroll
    for (int j = 0; j < 12; j++) {
        int idx = tid + 256 * j;
        ((uint4*)WtL)[idx] = ((const uint4*)WtP)[idx];
    }

    const int lane = tid & 63;
    const int wave = tid >> 6;
    const int n16 = lane & 15, quad = lane >> 4;
    const int wbase = wave * 64;
    // gather role: thread writes h-col = tid; logical edge eT with P(eT) = tid
    const int eT = 64 * (tid >> 6) + 16 * (tid & 3) + ((tid >> 2) & 15);

    const int qoff = (quad == 3) ? 0 : quad * 8;   // quad3: A bits don't-care (B k24..31 = 0)
    const short* Abase = WtL + n16 * WROW + qoff;  // + cb*16*WROW (imm)
    const float* hbase = hsT + wbase + n16 * 4;    // + c*EPB (imm); quad-broadcast, 2-way

    // B frags: quads 2 (bias row: bf16 1.0 at k=16) and 3 (zero) are TILE-INVARIANT.
    bf16x8 B0 = (bf16x8){0,0,0,0,0,0,0,0}, B1 = B0, B2 = B0, B3 = B0;
    if (quad == 2) {
        B0[0] = (short)0x3F80; B1[0] = (short)0x3F80;
        B2[0] = (short)0x3F80; B3[0] = (short)0x3F80;
    }

    const f32x4 Z = (f32x4){0, 0, 0, 0};
    const int chS = lane & 31, halfS = lane >> 5;   // scatter role

    int T = blockIdx.x;

    // ---- prologue: tile T state in registers
    int srow = src[eclamp(T * EPB + eT)];
    float4 h0, h1, h2, h3, h4, h5, h6, h7;
    {
        const float4* hp = (const float4*)(h + (size_t)srow * CH);
        h0 = hp[0]; h1 = hp[1]; h2 = hp[2]; h3 = hp[3];
        h4 = hp[4]; h5 = hp[5]; h6 = hp[6]; h7 = hp[7];
    }
    float4 e0, e1, e2, e3, e4, e5, e6, e7;
    if (quad < 2) {
        int b = T * EPB + wbase + n16;
        const float4* p;
        p = (const float4*)(ea + (size_t)eclamp(b)      * FE + quad * 8); e0 = p[0]; e1 = p[1];
        p = (const float4*)(ea + (size_t)eclamp(b + 16) * FE + quad * 8); e2 = p[0]; e3 = p[1];
        p = (const float4*)(ea + (size_t)eclamp(b + 32) * FE + quad * 8); e4 = p[0]; e5 = p[1];
        p = (const float4*)(ea + (size_t)eclamp(b + 48) * FE + quad * 8); e6 = p[0]; e7 = p[1];
    }
    int dv0, dv1, dv2, dv3;
    {
        int b = T * EPB + wbase + n16;
        dv0 = dst[eclamp(b)];      dv1 = dst[eclamp(b + 16)];
        dv2 = dst[eclamp(b + 32)]; dv3 = dst[eclamp(b + 48)];
    }
    if (quad < 2) { B0 = cvt8(e0, e1); B1 = cvt8(e2, e3); B2 = cvt8(e4, e5); B3 = cvt8(e6, e7); }
    srow = src[eclamp((T + PBLK) * EPB + eT)];   // src-row for NEXT tile

    while (true) {
        // stream this tile's h row into h-stage col = tid (bank = tid%32, 2-way free)
#define HST(c, v) hsT[(c) * EPB + tid] = (v)
        HST(0, h0.x);  HST(1, h0.y);  HST(2, h0.z);  HST(3, h0.w);
        HST(4, h1.x);  HST(5, h1.y);  HST(6, h1.z);  HST(7, h1.w);
        HST(8, h2.x);  HST(9, h2.y);  HST(10, h2.z); HST(11, h2.w);
        HST(12, h3.x); HST(13, h3.y); HST(14, h3.z); HST(15, h3.w);
        HST(16, h4.x); HST(17, h4.y); HST(18, h4.z); HST(19, h4.w);
        HST(20, h5.x); HST(21, h5.y); HST(22, h5.z); HST(23, h5.w);
        HST(24, h6.x); HST(25, h6.y); HST(26, h6.z); HST(27, h6.w);
        HST(28, h7.x); HST(29, h7.y); HST(30, h7.z); HST(31, h7.w);
#undef HST
        __syncthreads();                 // (a) h-stage ready (also fences WtL on iter 1)
        int nt = T + PBLK;
        bool more = (nt < NTILES);
        int dn0 = 0, dn1 = 0, dn2 = 0, dn3 = 0, srn = 0;
        if (more) {
            // prefetch next tile: flies under COMPUTE below
            const float4* hp = (const float4*)(h + (size_t)srow * CH);
            h0 = hp[0]; h1 = hp[1]; h2 = hp[2]; h3 = hp[3];
            h4 = hp[4]; h5 = hp[5]; h6 = hp[6]; h7 = hp[7];
            if (quad < 2) {
                int b = nt * EPB + wbase + n16;
                const float4* p;
                p = (const float4*)(ea + (size_t)eclamp(b)      * FE + quad * 8); e0 = p[0]; e1 = p[1];
                p = (const float4*)(ea + (size_t)eclamp(b + 16) * FE + quad * 8); e2 = p[0]; e3 = p[1];
                p = (const float4*)(ea + (size_t)eclamp(b + 32) * FE + quad * 8); e4 = p[0]; e5 = p[1];
                p = (const float4*)(ea + (size_t)eclamp(b + 48) * FE + quad * 8); e6 = p[0]; e7 = p[1];
            }
            int b = nt * EPB + wbase + n16;
            dn0 = dst[eclamp(b)];      dn1 = dst[eclamp(b + 16)];
            dn2 = dst[eclamp(b + 32)]; dn3 = dst[eclamp(b + 48)];
            srn = src[eclamp((nt + PBLK) * EPB + eT)];
        }

        // ---- COMPUTE tile T
        f32x4 m00 = Z, m01 = Z, m10 = Z, m11 = Z, m20 = Z, m21 = Z, m30 = Z, m31 = Z;
#pragma unroll
        for (int c = 0; c < 32; c++) {
            // hv[g] = h[edge 64w+16g+n16][c]; all quads same addr (broadcast), 2-way banks
            f32x4 hv = *(const f32x4*)(hbase + c * EPB);
            {
                bf16x8 A = *(const bf16x8*)(Abase + (c * 2 + 0) * (16 * WROW));
                f32x4 D0 = __builtin_amdgcn_mfma_f32_16x16x32_bf16(A, B0, Z, 0, 0, 0);
                f32x4 D1 = __builtin_amdgcn_mfma_f32_16x16x32_bf16(A, B1, Z, 0, 0, 0);
                f32x4 D2 = __builtin_amdgcn_mfma_f32_16x16x32_bf16(A, B2, Z, 0, 0, 0);
                f32x4 D3 = __builtin_amdgcn_mfma_f32_16x16x32_bf16(A, B3, Z, 0, 0, 0);
                m00 += lrelu4(D0) * hv[0]; m10 += lrelu4(D1) * hv[1];
                m20 += lrelu4(D2) * hv[2]; m30 += lrelu4(D3) * hv[3];
            }
            {
                bf16x8 A = *(const bf16x8*)(Abase + (c * 2 + 1) * (16 * WROW));
                f32x4 D0 = __builtin_amdgcn_mfma_f32_16x16x32_bf16(A, B0, Z, 0, 0, 0);
                f32x4 D1 = __builtin_amdgcn_mfma_f32_16x16x32_bf16(A, B1, Z, 0, 0, 0);
                f32x4 D2 = __builtin_amdgcn_mfma_f32_16x16x32_bf16(A, B2, Z, 0, 0, 0);
                f32x4 D3 = __builtin_amdgcn_mfma_f32_16x16x32_bf16(A, B3, Z, 0, 0, 0);
                m01 += lrelu4(D0) * hv[0]; m11 += lrelu4(D1) * hv[1];
                m21 += lrelu4(D2) * hv[2]; m31 += lrelu4(D3) * hv[3];
            }
        }

        __syncthreads();                 // (b) all COMPUTE done -> hsT reusable as msg

        // ---- msg transpose: lane (n16,quad) holds m[g][oh][r] for edge eloc=16g+n16,
        // ch=16oh+4q+r. col = wbase + (eloc+ch)&63 (wave-private; ~2-way write banks).
#pragma unroll
        for (int r = 0; r < 4; r++) {
            int c0 = quad * 4 + r, c1 = 16 + quad * 4 + r;
            hsT[c0 * EPB + wbase + ((n16 + c0) & 63)]      = m00[r];
            hsT[c1 * EPB + wbase + ((n16 + c1) & 63)]      = m01[r];
            hsT[c0 * EPB + wbase + ((16 + n16 + c0) & 63)] = m10[r];
            hsT[c1 * EPB + wbase + ((16 + n16 + c1) & 63)] = m11[r];
            hsT[c0 * EPB + wbase + ((32 + n16 + c0) & 63)] = m20[r];
            hsT[c1 * EPB + wbase + ((32 + n16 + c1) & 63)] = m21[r];
            hsT[c0 * EPB + wbase + ((48 + n16 + c0) & 63)] = m30[r];
            hsT[c1 * EPB + wbase + ((48 + n16 + c1) & 63)] = m31[r];
        }
        asm volatile("s_waitcnt lgkmcnt(0)" ::: "memory");  // same-wave write->read order

        // ---- coalesced scatter: pass p covers edges eloc2 = 2p + halfS of this wave;
        // lanes 0..31 / 32..63 = 32 consecutive ch of one dst row (128B contiguous).
        {
            int Tb = T * EPB + wbase;
#pragma unroll
            for (int p = 0; p < 32; p++) {
                int eloc2 = p * 2 + halfS;
                float v = hsT[chS * EPB + wbase + ((eloc2 + chS) & 63)];
                int dsel;
                if (p < 8) dsel = dv0; else if (p < 16) dsel = dv1;
                else if (p < 24) dsel = dv2; else dsel = dv3;
                int d = __shfl(dsel, eloc2 & 15, 64);      // dst row, uniform per half
                if (Tb + eloc2 < EE)
                    unsafeAtomicAdd(aggr + (size_t)d * CH + chS, v);
            }
        }

        if (!more) break;
        // rotate state -> next tile
        if (quad < 2) { B0 = cvt8(e0, e1); B1 = cvt8(e2, e3); B2 = cvt8(e4, e5); B3 = cvt8(e6, e7); }
        dv0 = dn0; dv1 = dn1; dv2 = dn2; dv3 = dn3;
        srow = srn;
        T = nt;
    }
}

// ---------------- Kernel 3 (MFMA): out = leaky(aggr + h@W_root + b_conv) @ W_out + b_out
__global__ void __launch_bounds__(256)
k_node(const float* __restrict__ aggr,
       const float* __restrict__ h,
       const float* __restrict__ W_root,
       const float* __restrict__ b_conv,
       const float* __restrict__ W_out,
       const float* __restrict__ b_out,
       float* __restrict__ out) {
    __shared__ short WrB[CH * 40];   // W_root^T bf16: [o][c], stride 40 shorts (80B)
    __shared__ float WoS[CH];
    int tid = threadIdx.x;
    if (tid < 128) {
        int o = tid >> 2, c0 = (tid & 3) * 8;
        short tmp[8] __attribute__((aligned(16)));
#pragma unroll
        for (int j = 0; j < 8; j++) tmp[j] = f2bf(W_root[(c0 + j) * CH + o]);
        *(bf16x8*)&WrB[o * 40 + c0] = *(bf16x8*)tmp;
    } else if (tid < 160) {
        WoS[tid - 128] = W_out[tid - 128];
    }
    __syncthreads();

    int wave = tid >> 6, lane = tid & 63;
    int n16 = lane & 15, quad = lane >> 4;
    int node0 = blockIdx.x * 64 + wave * 16;

    int arow = node0 + n16; if (arow >= NN) arow = NN - 1;
    const float4* hp = (const float4*)(h + (size_t)arow * CH + quad * 8);
    float4 ha = hp[0], hb = hp[1];
    bf16x8 A = cvt8(ha, hb);
    float bc0 = b_conv[n16], bc1 = b_conv[16 + n16];
    f32x4 C0, C1;
#pragma unroll
    for (int r = 0; r < 4; r++) {
        int nr = node0 + quad * 4 + r; int cr = (nr < NN) ? nr : NN - 1;
        C0[r] = aggr[(size_t)cr * CH + n16] + bc0;
        C1[r] = aggr[(size_t)cr * CH + 16 + n16] + bc1;
    }
    bf16x8 B0 = *(const bf16x8*)&WrB[n16 * 40 + quad * 8];
    bf16x8 B1 = *(const bf16x8*)&WrB[(16 + n16) * 40 + quad * 8];
    f32x4 D0 = __builtin_amdgcn_mfma_f32_16x16x32_bf16(A, B0, C0, 0, 0, 0);
    f32x4 D1 = __builtin_amdgcn_mfma_f32_16x16x32_bf16(A, B1, C1, 0, 0, 0);

    float w0 = WoS[n16], w1 = WoS[16 + n16];
    f32x4 p;
#pragma unroll
    for (int r = 0; r < 4; r++)
        p[r] = lrelu(D0[r]) * w0 + lrelu(D1[r]) * w1;
#pragma unroll
    for (int mk = 1; mk < 16; mk <<= 1) {
#pragma unroll
        for (int r = 0; r < 4; r++) p[r] += __shfl_xor(p[r], mk, 64);
    }
    if (n16 == 0) {
        float bo = b_out[0];
#pragma unroll
        for (int r = 0; r < 4; r++) {
            int nr = node0 + quad * 4 + r;
            if (nr < NN) out[nr] = p[r] + bo;
        }
    }
}

extern "C" void kernel_launch(void* const* d_in, const int* in_sizes, int n_in,
                              void* d_out, int out_size, void* d_ws, size_t ws_size,
                              hipStream_t stream) {
    const float* x      = (const float*)d_in[0];
    const int*   ei     = (const int*)d_in[1];
    const float* ea     = (const float*)d_in[2];
    const float* W_in   = (const float*)d_in[3];
    const float* b_in   = (const float*)d_in[4];
    const float* W_edge = (const float*)d_in[5];
    const float* b_edge = (const float*)d_in[6];
    const float* W_root = (const float*)d_in[7];
    const float* b_conv = (const float*)d_in[8];
    const float* W_out  = (const float*)d_in[9];
    const float* b_out  = (const float*)d_in[10];
    float* out  = (float*)d_out;
    float* h    = (float*)d_ws;                  // [NN*CH] f32
    float* aggr = h + (size_t)NN * CH;           // [NN*CH] f32
    short* WtP  = (short*)(aggr + (size_t)NN * CH);  // [WTP_SHORTS] bf16 image

    k_pre<<<PROJ_BLOCKS + AUX_BLOCKS, 256, 0, stream>>>(x, W_in, b_in, W_edge, b_edge,
                                                        h, aggr, WtP);
    k_edge<<<PBLK, 256, 0, stream>>>(WtP, ea, ei, ei + EE, h, aggr);
    k_node<<<PROJ_BLOCKS, 256, 0, stream>>>(aggr, h, W_root, b_conv, W_out, b_out, out);
}

// Round 7
// 170.153 us; speedup vs baseline: 6.4658x; 1.0976x over previous
//
#include <hip/hip_runtime.h>

#define NN 25000
#define EE 400000
#define FIN 128
#define FE 16
#define CH 32
#define SLOPE 0.01f
#define PROJ_BLOCKS 391   // ceil(25000/64)
#define AUX_BLOCKS 32
#define W16_SHORTS (1024 * 16)       // 32KB weight image, 16 shorts/row (bias separate)
#define EPT 128                      // edges per k_edge tile (EE % EPT == 0 -> no guards)
#define NT (EE / EPT)                // 3125 tiles
#define PBLK 768                     // persistent blocks = 3 per CU (52KB LDS)

typedef __attribute__((ext_vector_type(8))) short bf16x8;
typedef __attribute__((ext_vector_type(4))) float f32x4;

__device__ __forceinline__ float lrelu(float v) { return fmaxf(v, SLOPE * v); }

__device__ __forceinline__ f32x4 lrelu4(f32x4 v) {
    f32x4 s = v * SLOPE;
#if __has_builtin(__builtin_elementwise_max)
    return __builtin_elementwise_max(v, s);   // v_pk_max_f32
#else
    f32x4 r;
    r[0] = fmaxf(v[0], s[0]); r[1] = fmaxf(v[1], s[1]);
    r[2] = fmaxf(v[2], s[2]); r[3] = fmaxf(v[3], s[3]);
    return r;
#endif
}

// float -> bf16 bits, round-to-nearest-even
__device__ __forceinline__ short f2bf(float f) {
    union { float f; unsigned u; } v; v.f = f;
    unsigned r = (v.u + 0x7fffu + ((v.u >> 16) & 1u)) >> 16;
    return (short)r;
}

__device__ __forceinline__ bf16x8 cvt8(const float4& a, const float4& b) {
    return (bf16x8){f2bf(a.x), f2bf(a.y), f2bf(a.z), f2bf(a.w),
                    f2bf(b.x), f2bf(b.y), f2bf(b.z), f2bf(b.w)};
}

// ---------------- Kernel 1: fused prep
// blocks [0, PROJ_BLOCKS): h = leaky(x @ W_in + b_in) via MFMA (64 nodes/block)
// blocks [PROJ, +4): WtP16[co][16] = bf16 W_edge^T row (plain; k_edge applies swizzle)
// blocks [+4, +32): zero aggr
__global__ void __launch_bounds__(256)
k_pre(const float* __restrict__ x, const float* __restrict__ W_in,
      const float* __restrict__ b_in, const float* __restrict__ W_edge,
      const float* __restrict__ b_edge,
      float* __restrict__ h, float* __restrict__ aggr, short* __restrict__ WtP16) {
    __shared__ short Wt1[CH * 136];
    int tid = threadIdx.x;

    if (blockIdx.x >= PROJ_BLOCKS) {
        int ab = blockIdx.x - PROJ_BLOCKS;
        if (ab < 4) {
            int co = ab * 256 + tid;                       // 0..1023
            short row[16] __attribute__((aligned(16)));
#pragma unroll
            for (int k = 0; k < 16; k++) row[k] = f2bf(W_edge[k * 1024 + co]);
            uint4* dstp = (uint4*)(WtP16 + co * 16);       // co*32B, 16B-aligned
            dstp[0] = ((uint4*)row)[0]; dstp[1] = ((uint4*)row)[1];
        } else {
            int t = (ab - 4) * 256 + tid;
            float4 z = make_float4(0.f, 0.f, 0.f, 0.f);
            for (int i = t; i < NN * CH / 4; i += (AUX_BLOCKS - 4) * 256)
                ((float4*)aggr)[i] = z;
        }
        return;
    }

#pragma unroll
    for (int i = 0; i < 16; i++) {
        int id = tid + 256 * i;           // id = k*32 + c
        int k = id >> 5, c = id & 31;
        Wt1[c * 136 + k] = f2bf(W_in[id]);
    }
    __syncthreads();

    int wave = tid >> 6, lane = tid & 63;
    int n16 = lane & 15, quad = lane >> 4;
    int node0 = blockIdx.x * 64 + wave * 16;

    f32x4 D[2];
#pragma unroll
    for (int ch = 0; ch < 2; ch++) {
        float bb = b_in[ch * 16 + n16];
        D[ch] = (f32x4){bb, bb, bb, bb};
    }
    int arow = node0 + n16; if (arow >= NN) arow = NN - 1;
#pragma unroll
    for (int kb = 0; kb < 4; kb++) {
        const float4* xp = (const float4*)(x + (size_t)arow * FIN + kb * 32 + quad * 8);
        float4 xa = xp[0], xb = xp[1];
        bf16x8 A = cvt8(xa, xb);
#pragma unroll
        for (int ch = 0; ch < 2; ch++) {
            bf16x8 B = *(const bf16x8*)&Wt1[(ch * 16 + n16) * 136 + kb * 32 + quad * 8];
            D[ch] = __builtin_amdgcn_mfma_f32_16x16x32_bf16(A, B, D[ch], 0, 0, 0);
        }
    }
#pragma unroll
    for (int ch = 0; ch < 2; ch++)
#pragma unroll
        for (int r = 0; r < 4; r++) {
            int nn = node0 + quad * 4 + r;
            if (nn < NN) h[(size_t)nn * CH + ch * 16 + n16] = lrelu(D[ch][r]);
        }
}

// ---------------- Kernel 2: persistent edge kernel, R3 orientation, 52KB LDS
// D[edge][co] = mfma(A = ea-frags (regs), B = W16 rows (LDS), C = bias splat).
// LDS = W16 32KB + biasF 4KB + hsT[32][128] 16KB = 53248 B -> 3 blocks/CU
// = 12 waves/CU (was 8). Latency-bound kernel (all pipes <30%/SIMD per R6 PMC),
// so waves/SIMD 2->3 is the lever. Bias via MFMA C-input (D col = co => one
// scalar/lane/MFMA, ds_read2-pair, bank-free). Quads 2/3: A==0, B-read aliases
// slots 0/1 (don't-care). B-read slot-XOR qeff=(q&1)^((n16>>2)&1) (store-side
// matches) breaks the natural 4-way bank collision -> ~2-way (free).
// Scatter: direct 64B-coalesced atomics (proven 50MB WRITE). 2 barriers/tile.
// __launch_bounds__(256,2): cap 128 VGPR; R3's near-identical body measured 88.
__global__ void __launch_bounds__(256, 2)
k_edge(const short* __restrict__ WtP16,  // [1024][16] bf16 image (plain layout)
       const float* __restrict__ ea,     // [EE][16] f32
       const int* __restrict__ src,
       const int* __restrict__ dst,
       const float* __restrict__ h,
       float* __restrict__ aggr,
       const float* __restrict__ b_edge) {
    __shared__ short W16[W16_SHORTS];        // 32768 B (slot-swizzled)
    __shared__ float biasF[1024];            //  4096 B (raw f32 b_edge)
    __shared__ float hsT[CH * EPT];          // 16384 B, hsT[c][e]

    int tid = threadIdx.x;

    // stage: 2048 uint4 W16 (swizzled) + 256 uint4 biasF = 9 iters/thread
#pragma unroll
    for (int j = 0; j < 9; j++) {
        int idx = tid + 256 * j;
        if (idx < 2048) {
            int co = idx >> 1, s = idx & 1;
            int p = (co << 1) | (s ^ ((co >> 2) & 1));     // slot-XOR
            ((uint4*)W16)[p] = ((const uint4*)WtP16)[idx];
        } else if (idx < 2304) {
            ((uint4*)biasF)[idx - 2048] = ((const uint4*)b_edge)[idx - 2048];
        }
    }

    const int lane = tid & 63;
    const int wave = tid >> 6;
    const int n16 = lane & 15, quad = lane >> 4;
    const int t0 = wave * 32, t1 = t0 + 16;
    const int eH = tid >> 1, halfH = tid & 1;      // gather role

    // B base: row co = cb*16+n16, phys slot = (q&1) ^ ((co>>2)&1); (co>>2)&1 == (n16>>2)&1
    const int qeff = (quad & 1) ^ ((n16 >> 2) & 1);
    const short* Bbase = W16 + n16 * 16 + qeff * 8;          // + cb*256 shorts (imm)
    const float* h0b = hsT + t0 + quad * 4;                  // + c*EPT (imm)
    const float* h1b = hsT + t1 + quad * 4;

    struct PrefT {
        float hv[16];
        float4 e0a, e0b, e1a, e1b;
        int d[8];
    };
    PrefT Pa, Pb;

    auto PREF = [&](int tile, PrefT& P) {
        int base = tile * EPT;
        int s = src[base + eH];
        const float4* hp = (const float4*)(h + (size_t)s * CH + halfH * 16);
        float4 v0 = hp[0], v1 = hp[1], v2 = hp[2], v3 = hp[3];
        *(float4*)&P.hv[0] = v0;  *(float4*)&P.hv[4] = v1;
        *(float4*)&P.hv[8] = v2;  *(float4*)&P.hv[12] = v3;
        if (quad < 2) {
            const float4* p0 = (const float4*)(ea + (size_t)(base + t0 + n16) * FE + quad * 8);
            P.e0a = p0[0]; P.e0b = p0[1];
            const float4* p1 = (const float4*)(ea + (size_t)(base + t1 + n16) * FE + quad * 8);
            P.e1a = p1[0]; P.e1b = p1[1];
        }
#pragma unroll
        for (int r = 0; r < 4; r++) {
            P.d[r]     = dst[base + t0 + quad * 4 + r];
            P.d[4 + r] = dst[base + t1 + quad * 4 + r];
        }
    };

    auto WRITE = [&](PrefT& P) {
        // addr = (halfH*16+j)*128 + eH -> bank eH%32, 2 lanes/bank = free
        float* hd = hsT + halfH * (16 * EPT) + eH;
#pragma unroll
        for (int j = 0; j < 16; j++) hd[j * EPT] = P.hv[j];
    };

    auto COMPUTE = [&](PrefT& P) {
        bf16x8 A0 = (bf16x8){0,0,0,0,0,0,0,0}, A1 = A0;    // quads 2,3: A==0 (k 16..31)
        if (quad < 2) { A0 = cvt8(P.e0a, P.e0b); A1 = cvt8(P.e1a, P.e1b); }

        f32x4 m0[2], m1[2];
        m0[0] = (f32x4){0,0,0,0}; m0[1] = m0[0]; m1[0] = m0[0]; m1[1] = m0[0];

#pragma unroll
        for (int c = 0; c < 32; c++) {
            f32x4 hc0 = *(const f32x4*)(h0b + c * EPT);    // quad-disjoint banks, free
            f32x4 hc1 = *(const f32x4*)(h1b + c * EPT);
            float b0 = biasF[32 * c + n16];                // pair 64B apart -> ds_read2
            float b1 = biasF[32 * c + 16 + n16];
            f32x4 Cb0 = (f32x4){b0, b0, b0, b0};
            f32x4 Cb1 = (f32x4){b1, b1, b1, b1};
            {
                bf16x8 B = *(const bf16x8*)(Bbase + (2 * c) * 256);
                f32x4 D0 = __builtin_amdgcn_mfma_f32_16x16x32_bf16(A0, B, Cb0, 0, 0, 0);
                f32x4 D1 = __builtin_amdgcn_mfma_f32_16x16x32_bf16(A1, B, Cb0, 0, 0, 0);
                m0[0] += lrelu4(D0) * hc0;
                m1[0] += lrelu4(D1) * hc1;
            }
            {
                bf16x8 B = *(const bf16x8*)(Bbase + (2 * c + 1) * 256);
                f32x4 D0 = __builtin_amdgcn_mfma_f32_16x16x32_bf16(A0, B, Cb1, 0, 0, 0);
                f32x4 D1 = __builtin_amdgcn_mfma_f32_16x16x32_bf16(A1, B, Cb1, 0, 0, 0);
                m0[1] += lrelu4(D0) * hc0;
                m1[1] += lrelu4(D1) * hc1;
            }
        }

        // scatter: lanes n16 = 16 consecutive channels of one row -> 64B segments.
        // No bounds guards: EE % EPT == 0 (all tiles full).
#pragma unroll
        for (int r = 0; r < 4; r++) {
#pragma unroll
            for (int oh = 0; oh < 2; oh++) {
                unsafeAtomicAdd(&aggr[(size_t)P.d[r]     * CH + oh * 16 + n16], m0[oh][r]);
                unsafeAtomicAdd(&aggr[(size_t)P.d[4 + r] * CH + oh * 16 + n16], m1[oh][r]);
            }
        }
    };

    // persistent loop, 2-phase unrolled (static Pa/Pb). Single hsT buffer:
    // sync(a) = prev COMPUTE done (iter 1: staging fence); sync(b) = hsT ready.
    int T = blockIdx.x;
    PREF(T, Pa);
    while (true) {
        __syncthreads();
        WRITE(Pa);
        __syncthreads();
        int nt = T + PBLK;
        bool more = (nt < NT);
        if (more) PREF(nt, Pb);          // flies under COMPUTE
        COMPUTE(Pa);
        if (!more) break;
        T = nt;

        __syncthreads();
        WRITE(Pb);
        __syncthreads();
        nt = T + PBLK;
        more = (nt < NT);
        if (more) PREF(nt, Pa);
        COMPUTE(Pb);
        if (!more) break;
        T = nt;
    }
}

// ---------------- Kernel 3 (MFMA): out = leaky(aggr + h@W_root + b_conv) @ W_out + b_out
__global__ void __launch_bounds__(256)
k_node(const float* __restrict__ aggr,
       const float* __restrict__ h,
       const float* __restrict__ W_root,
       const float* __restrict__ b_conv,
       const float* __restrict__ W_out,
       const float* __restrict__ b_out,
       float* __restrict__ out) {
    __shared__ short WrB[CH * 40];   // W_root^T bf16: [o][c], stride 40 shorts (80B)
    __shared__ float WoS[CH];
    int tid = threadIdx.x;
    if (tid < 128) {
        int o = tid >> 2, c0 = (tid & 3) * 8;
        short tmp[8] __attribute__((aligned(16)));
#pragma unroll
        for (int j = 0; j < 8; j++) tmp[j] = f2bf(W_root[(c0 + j) * CH + o]);
        *(bf16x8*)&WrB[o * 40 + c0] = *(bf16x8*)tmp;
    } else if (tid < 160) {
        WoS[tid - 128] = W_out[tid - 128];
    }
    __syncthreads();

    int wave = tid >> 6, lane = tid & 63;
    int n16 = lane & 15, quad = lane >> 4;
    int node0 = blockIdx.x * 64 + wave * 16;

    int arow = node0 + n16; if (arow >= NN) arow = NN - 1;
    const float4* hp = (const float4*)(h + (size_t)arow * CH + quad * 8);
    float4 ha = hp[0], hb = hp[1];
    bf16x8 A = cvt8(ha, hb);
    float bc0 = b_conv[n16], bc1 = b_conv[16 + n16];
    f32x4 C0, C1;
#pragma unroll
    for (int r = 0; r < 4; r++) {
        int nr = node0 + quad * 4 + r; int cr = (nr < NN) ? nr : NN - 1;
        C0[r] = aggr[(size_t)cr * CH + n16] + bc0;
        C1[r] = aggr[(size_t)cr * CH + 16 + n16] + bc1;
    }
    bf16x8 B0 = *(const bf16x8*)&WrB[n16 * 40 + quad * 8];
    bf16x8 B1 = *(const bf16x8*)&WrB[(16 + n16) * 40 + quad * 8];
    f32x4 D0 = __builtin_amdgcn_mfma_f32_16x16x32_bf16(A, B0, C0, 0, 0, 0);
    f32x4 D1 = __builtin_amdgcn_mfma_f32_16x16x32_bf16(A, B1, C1, 0, 0, 0);

    float w0 = WoS[n16], w1 = WoS[16 + n16];
    f32x4 p;
#pragma unroll
    for (int r = 0; r < 4; r++)
        p[r] = lrelu(D0[r]) * w0 + lrelu(D1[r]) * w1;
#pragma unroll
    for (int mk = 1; mk < 16; mk <<= 1) {
#pragma unroll
        for (int r = 0; r < 4; r++) p[r] += __shfl_xor(p[r], mk, 64);
    }
    if (n16 == 0) {
        float bo = b_out[0];
#pragma unroll
        for (int r = 0; r < 4; r++) {
            int nr = node0 + quad * 4 + r;
            if (nr < NN) out[nr] = p[r] + bo;
        }
    }
}

extern "C" void kernel_launch(void* const* d_in, const int* in_sizes, int n_in,
                              void* d_out, int out_size, void* d_ws, size_t ws_size,
                              hipStream_t stream) {
    const float* x      = (const float*)d_in[0];
    const int*   ei     = (const int*)d_in[1];
    const float* ea     = (const float*)d_in[2];
    const float* W_in   = (const float*)d_in[3];
    const float* b_in   = (const float*)d_in[4];
    const float* W_edge = (const float*)d_in[5];
    const float* b_edge = (const float*)d_in[6];
    const float* W_root = (const float*)d_in[7];
    const float* b_conv = (const float*)d_in[8];
    const float* W_out  = (const float*)d_in[9];
    const float* b_out  = (const float*)d_in[10];
    float* out  = (float*)d_out;
    float* h    = (float*)d_ws;                  // [NN*CH] f32
    float* aggr = h + (size_t)NN * CH;           // [NN*CH] f32
    short* WtP16 = (short*)(aggr + (size_t)NN * CH);  // [1024*16] bf16 image

    k_pre<<<PROJ_BLOCKS + AUX_BLOCKS, 256, 0, stream>>>(x, W_in, b_in, W_edge, b_edge,
                                                        h, aggr, WtP16);
    k_edge<<<PBLK, 256, 0, stream>>>(WtP16, ea, ei, ei + EE, h, aggr, b_edge);
    k_node<<<PROJ_BLOCKS, 256, 0, stream>>>(aggr, h, W_root, b_conv, W_out, b_out, out);
}